// Round 10
// baseline (522.365 us; speedup 1.0000x reference)
//
#include <hip/hip_runtime.h>
#include <hip/hip_bf16.h>
#include <math.h>

typedef __hip_bfloat16 bf16;
typedef __bf16 bf16x8 __attribute__((ext_vector_type(8)));
typedef float f32x4 __attribute__((ext_vector_type(4)));

#define B_ 8
#define T_ 2048
#define D_ 512
#define H_ 2048

__device__ __forceinline__ float b2f(unsigned short u) {
    return __uint_as_float((unsigned)u << 16);
}
__device__ __forceinline__ float ldf(const float* p, long i) { return p[i]; }
__device__ __forceinline__ float ldf(const bf16* p, long i) {
    return b2f(((const unsigned short*)p)[i]);
}
// tanh-form gelu: v*sigmoid(1.59577(v+0.044715 v^3)); |err| < 1e-3 abs
__device__ __forceinline__ float gelu_f(float v) {
    float a = 1.5957691216057308f * (v + 0.044715f * v * v * v);
    return v / (1.0f + __expf(-a));
}

// Packed (tile-major) layout for GEMM-staged operands:
// tile = 16 rows x 32 cols (1 KB bf16) = exactly one wave's global_load_lds
// payload in LDS dest order: within-tile offset = (row&15)*32 + (col&31).
//   off(row,col,K) = ((row>>4)*(K>>5) + (col>>5))*512 + (row&15)*32 + (col&31)
// => staging is fully-contiguous 1KB bursts (FETCH 138->25MB measured, R5).
__device__ __forceinline__ long poff(int row, int col, int K) {
    return ((long)(row >> 4) * (K >> 5) + (col >> 5)) * 512 + (row & 15) * 32 + (col & 31);
}

#define GLD16(g, l)                                                          \
    __builtin_amdgcn_global_load_lds(                                        \
        (const __attribute__((address_space(1))) void*)(g),                  \
        (__attribute__((address_space(3))) void*)(l), 16, 0, 0)

// ---------------- LayerNorm body over D=512, 256 threads, one row -----------------
template <typename Tin, bool PACKO>
__device__ __forceinline__ void ln_body(const Tin* __restrict__ x,
                                        const float* __restrict__ g,
                                        const float* __restrict__ bb,
                                        bf16* __restrict__ y, int row, int tid,
                                        float* red) {
    long base = (long)row * D_;
    float v0 = ldf(x, base + tid);
    float v1 = ldf(x, base + tid + 256);
    float s = v0 + v1;
#pragma unroll
    for (int off = 32; off > 0; off >>= 1) s += __shfl_down(s, off);
    int lane = tid & 63, wid = tid >> 6;
    if (lane == 0) red[wid] = s;
    __syncthreads();
    float mean = (red[0] + red[1] + red[2] + red[3]) * (1.0f / 512.0f);
    __syncthreads();
    float d0 = v0 - mean, d1 = v1 - mean;
    float vs = d0 * d0 + d1 * d1;
#pragma unroll
    for (int off = 32; off > 0; off >>= 1) vs += __shfl_down(vs, off);
    if (lane == 0) red[wid] = vs;
    __syncthreads();
    float var = (red[0] + red[1] + red[2] + red[3]) * (1.0f / 512.0f);
    float rstd = rsqrtf(var + 1e-5f);
    float o0 = d0 * rstd * g[tid] + bb[tid];
    float o1 = d1 * rstd * g[tid + 256] + bb[tid + 256];
    if (PACKO) {
        y[poff(row, tid, D_)]       = __float2bfloat16(o0);
        y[poff(row, tid + 256, D_)] = __float2bfloat16(o1);
    } else {
        y[base + tid]       = __float2bfloat16(o0);
        y[base + tid + 256] = __float2bfloat16(o1);
    }
}

// ---------------- standalone LN (step 10 only) ----------------
template <typename Tin, bool PACKO>
__global__ __launch_bounds__(256) void ln_kernel(const Tin* __restrict__ x,
                                                 const float* __restrict__ g,
                                                 const float* __restrict__ bb,
                                                 bf16* __restrict__ y) {
    __shared__ float red[4];
    ln_body<Tin, PACKO>(x, g, bb, y, blockIdx.x, threadIdx.x, red);
}

struct WT6 {
    const float* src[6];
    bf16* dst[6];
    int K[6], N[6];
};

// -------- PREP: one launch = wtrans(6144 blocks) + LN1(16384) + expw(2048) -------
// All three depend only on kernel inputs (launch-overhead reduction: 11->8).
__global__ __launch_bounds__(256) void prep_kernel(WT6 p,
                                                   const float* __restrict__ x,
                                                   const float* __restrict__ ln1g,
                                                   const float* __restrict__ ln1b,
                                                   bf16* __restrict__ h1,
                                                   const float* __restrict__ w,
                                                   bf16* __restrict__ ew) {
    __shared__ float sbuf[64][65];
    int bid = blockIdx.x;
    int tid = threadIdx.x;
    if (bid < 6144) {
        // weight transpose + f32->bf16, PACKED: W[K,N] -> WT[N,K]
        int z = bid >> 10;
        int rem = bid & 1023;
        int n0 = (rem & 31) * 64, k0 = (rem >> 5) * 64;
        int K = p.K[z], N = p.N[z];
        if (n0 >= N || k0 >= K) return;
        const float* W = p.src[z];
        bf16* WT = p.dst[z];
        int tx = tid & 63, ty = tid >> 6;
#pragma unroll
        for (int r = 0; r < 16; ++r) {
            int kl = r * 4 + ty;
            sbuf[kl][tx] = W[(long)(k0 + kl) * N + n0 + tx];
        }
        __syncthreads();
#pragma unroll
        for (int r = 0; r < 16; ++r) {
            int nl = r * 4 + ty;
            WT[poff(n0 + nl, k0 + tx, K)] = __float2bfloat16(sbuf[tx][nl]);
        }
    } else if (bid < 6144 + 16384) {
        // LN1 (packed output)
        ln_body<float, true>(x, ln1g, ln1b, h1, bid - 6144, tid, &sbuf[0][0]);
    } else {
        // exp(w - rowmax(w)), packed output
        int row = bid - (6144 + 16384);
        long base = (long)row * T_;
        float v[8];
        float mx = -3.4e38f;
#pragma unroll
        for (int i = 0; i < 8; ++i) {
            v[i] = w[base + tid + i * 256];
            mx = fmaxf(mx, v[i]);
        }
#pragma unroll
        for (int off = 32; off > 0; off >>= 1) mx = fmaxf(mx, __shfl_down(mx, off));
        float* red = &sbuf[0][0];
        if ((tid & 63) == 0) red[tid >> 6] = mx;
        __syncthreads();
        float rmax = fmaxf(fmaxf(red[0], red[1]), fmaxf(red[2], red[3]));
#pragma unroll
        for (int i = 0; i < 8; ++i)
            ew[poff(row, tid + i * 256, T_)] = __float2bfloat16(expf(v[i] - rmax));
    }
}

// -------- MKV: fused maxk + kv2t (one launch; mk buffer eliminated) --------------
// Per (t0,d0) 64x64 tile: pass 1 computes max over b in-register; pass 2 writes
// kv2t[b] PACKED with 16-col-group num/den interleave:
//   d -> num_row = (d>>4)*32 + (d&15), den_row = num_row + 16
// so in s7 a wave's ni-even fragment is num and ni-odd the SAME d's den (same
// lane) -> divergence-free fused-Yt epilogue (fixes R9's half-idle epilogue).
__global__ __launch_bounds__(256) void mkv_kernel(const bf16* __restrict__ K_,
                                                  const bf16* __restrict__ V_,
                                                  bf16* __restrict__ kv2t) {
    __shared__ float sev[64][65];
    __shared__ float se[64][65];
    int tx = threadIdx.x & 63, ty = threadIdx.x >> 6;
    int t0 = blockIdx.x * 64, d0 = blockIdx.y * 64;
    float mx[16];
#pragma unroll
    for (int r = 0; r < 16; ++r) mx[r] = -3.4e38f;
    for (int b = 0; b < B_; ++b) {
        long ibase = (long)b << 20;
#pragma unroll
        for (int r = 0; r < 16; ++r) {
            long mi = (long)(t0 + r * 4 + ty) * D_ + d0 + tx;
            mx[r] = fmaxf(mx[r], ldf(K_, ibase + mi));
        }
    }
    for (int b = 0; b < B_; ++b) {
        long ibase = (long)b << 20;
#pragma unroll
        for (int r = 0; r < 16; ++r) {
            int tl = r * 4 + ty;
            long mi = (long)(t0 + tl) * D_ + d0 + tx;
            float e = expf(ldf(K_, ibase + mi) - mx[r]);
            sev[tl][tx] = e * ldf(V_, ibase + mi);
            se[tl][tx] = e;
        }
        __syncthreads();
        long obase = (long)b << 21;
#pragma unroll
        for (int r = 0; r < 16; ++r) {
            int d = d0 + r * 4 + ty;
            int nrow = ((d >> 4) << 5) + (d & 15);
            kv2t[obase + poff(nrow,      t0 + tx, T_)] = __float2bfloat16(sev[tx][r * 4 + ty]);
            kv2t[obase + poff(nrow + 16, t0 + tx, T_)] = __float2bfloat16(se[tx][r * 4 + ty]);
        }
        __syncthreads();
    }
}

// ---------------- MFMA GEMM: C = epi(A@Bt^T + bias) [+res] ------------------------
// R6-proven body: 128x128 macro-tile, 4 waves, 2-buffer LDS, plain C++ LDS reads,
// __syncthreads per K-step, packed 1KB-burst staging, 3D chunked XCD swizzle.
// (R7/R8 ablations: moving either operand to direct-global regressed — LDS-DMA +
// multi-block TLP is the best schedule for this 2-phase structure; keep it.)
// yq != null (s7 only): FUSED-Yt epilogue, divergence-free. B rows carry
// 16-col-group interleaved num/den (see mkv): acc[mi][2p]=num, acc[mi][2p+1]=den
// for d = (n0+wn*64)/2 + p*16 + cc. Writes Yt = sigQ*num/den in place into yq.
// PK bit0: A packed; bit1: B packed; bit2: C written packed (non-plane path).
// planeStride!=0: N split into 512-col planes; per-plane bias b0/b1/b2 and
// mode=(modes>>(2*plane))&3. mode 0=none 1=sigmoid 2=gelu.
template <int BM, int PK>
__global__ __launch_bounds__(256, 4) void mfma_gemm(
    const bf16* __restrict__ A, const bf16* __restrict__ Bt,
    const float* __restrict__ b0, const float* __restrict__ b1,
    const float* __restrict__ b2,
    bf16* __restrict__ Cb, float* __restrict__ Cf,
    const bf16* __restrict__ resb, const float* __restrict__ resf,
    bf16* __restrict__ yq,
    int M, int N, int K, int modes, long bsB, long bsC, long planeStride) {
    constexpr int MI = BM / 32;
    constexpr int NA = BM / 64;
    constexpr int PL = (BM + 128) * 32;  // shorts per LDS buffer plane
    constexpr bool PA = PK & 1, PB = PK & 2, PCK = PK & 4;
    constexpr long astep = PA ? 512 : 32;
    constexpr long bstep = PB ? 512 : 32;
    __shared__ short Sh[2 * PL];         // 2 bufs: 32KB @BM=128
    int tid = threadIdx.x;
    int lane = tid & 63, wave = tid >> 6;
    int wm = wave & 1, wn = wave >> 1;

    // 3D chunked XCD swizzle (nwg % 8 == 0 for every launch here)
    int gx = gridDim.x, gy = gridDim.y;
    long nwg = (long)gx * gy * gridDim.z;
    long o = blockIdx.x + (long)gx * (blockIdx.y + (long)gy * blockIdx.z);
    long wk = (o & 7) * (nwg >> 3) + (o >> 3);
    int bx = (int)(wk % gx);
    long rq = wk / gx;
    int by = (int)(rq % gy);
    int bz = (int)(rq / gy);
    int m0 = by * BM, n0 = bx * 128;

    const short* Ag = (const short*)A;
    const short* Bg = (const short*)Bt + (long)bz * bsB;

    int lr = lane >> 2;
    int le = (lane & 3) * 8;
    const short* ga[NA];
    short* la[NA];
#pragma unroll
    for (int i = 0; i < NA; ++i) {
        int arow = m0 + wave * (BM / 4) + i * 16;
        ga[i] = PA ? Ag + (long)(arow >> 4) * ((long)K << 4) + lane * 8
                   : Ag + (long)(arow + lr) * K + le;
        la[i] = Sh + (wave * (BM / 4) + i * 16) * 32;
    }
    int brow = n0 + wave * 32;
    const short* gb0 = PB ? Bg + (long)(brow >> 4) * ((long)K << 4) + lane * 8
                          : Bg + (long)(brow + lr) * K + le;
    const short* gb1 = PB ? gb0 + ((long)K << 4) : gb0 + 16L * K;
    short* lb0 = Sh + BM * 32 + (wave * 32) * 32;
    short* lb1 = lb0 + 16 * 32;

    f32x4 acc[MI][4];
    f32x4 zz = {0.f, 0.f, 0.f, 0.f};
#pragma unroll
    for (int i = 0; i < MI; ++i)
#pragma unroll
        for (int j = 0; j < 4; ++j) acc[i][j] = zz;

    int fr = lane & 15;
    int fk = (lane >> 4) * 8;
    int rm = wm * (BM / 2);

    auto stage = [&](int kt, int ofs) {
#pragma unroll
        for (int i = 0; i < NA; ++i) GLD16(ga[i] + kt * astep, la[i] + ofs);
        GLD16(gb0 + kt * bstep, lb0 + ofs);
        GLD16(gb1 + kt * bstep, lb1 + ofs);
    };
    auto compute = [&](int ofs) {
        const short* Asb = Sh + ofs;
        const short* Bsb = Sh + ofs + BM * 32;
        bf16x8 af[MI], bv[4];
#pragma unroll
        for (int mi = 0; mi < MI; ++mi)
            af[mi] = *(const bf16x8*)(Asb + (rm + mi * 16 + fr) * 32 + fk);
#pragma unroll
        for (int ni = 0; ni < 4; ++ni)
            bv[ni] = *(const bf16x8*)(Bsb + (wn * 64 + ni * 16 + fr) * 32 + fk);
#pragma unroll
        for (int mi = 0; mi < MI; ++mi)
#pragma unroll
            for (int ni = 0; ni < 4; ++ni)
                acc[mi][ni] = __builtin_amdgcn_mfma_f32_16x16x32_bf16(
                    af[mi], bv[ni], acc[mi][ni], 0, 0, 0);
    };

    // ---- 2-buffer pipelined K loop (nk even for all shapes used: K=512/2048) ----
    int nk = K >> 5;
    stage(0, 0);
    __syncthreads();
    for (int kt = 0; kt < nk; kt += 2) {
        if (kt + 1 < nk) stage(kt + 1, PL);
        compute(0);
        __syncthreads();
        if (kt + 2 < nk) stage(kt + 2, 0);
        compute(PL);
        __syncthreads();
    }

    int cc = lane & 15, cr = (lane >> 4) * 4;
    if (yq) {
        // ---- fused-Yt epilogue (s7): all lanes active, no shfl ----
        long qb = (long)bz * (long)(T_ * D_);
        int dbase = (n0 + wn * 64) >> 1;
#pragma unroll
        for (int mi = 0; mi < MI; ++mi) {
            int row0 = m0 + rm + mi * 16 + cr;
#pragma unroll
            for (int pp = 0; pp < 2; ++pp) {
                int d = dbase + pp * 16 + cc;
#pragma unroll
                for (int r = 0; r < 4; ++r) {
                    long qi = qb + (long)(row0 + r) * D_ + d;
                    float sq = ldf((const bf16*)yq, qi);
                    yq[qi] = __float2bfloat16(sq * acc[mi][2 * pp][r] /
                                              acc[mi][2 * pp + 1][r]);
                }
            }
        }
        return;
    }
    long cbase = (long)bz * bsC;
#pragma unroll
    for (int mi = 0; mi < MI; ++mi) {
#pragma unroll
        for (int ni = 0; ni < 4; ++ni) {
            int row0 = m0 + rm + mi * 16 + cr;
            int col = n0 + wn * 64 + ni * 16 + cc;
            float bvl;
            long colterm;
            int md, rowstride;
            if (planeStride) {
                int plane = col >> 9;
                int c2 = col & 511;
                const float* bp = (plane == 0) ? b0 : ((plane == 1) ? b1 : b2);
                bvl = bp[c2];
                md = (modes >> (2 * plane)) & 3;
                colterm = (long)plane * planeStride + c2;
                rowstride = 512;
            } else {
                bvl = b0 ? b0[col] : 0.0f;
                md = modes & 3;
                colterm = col;
                rowstride = N;
            }
#pragma unroll
            for (int r = 0; r < 4; ++r) {
                float v = acc[mi][ni][r] + bvl;
                if (md == 1) v = 1.0f / (1.0f + __expf(-v));
                else if (md == 2) v = gelu_f(v);
                long idx;
                if (PCK) idx = cbase + poff(row0 + r, col, N);
                else     idx = cbase + (long)(row0 + r) * rowstride + colterm;
                if (resf) v += resf[idx];
                if (resb) v += ldf(resb, idx);
                if (Cf) Cf[idx] = v;
                else Cb[idx] = __float2bfloat16(v);
            }
        }
    }
}

extern "C" void kernel_launch(void* const* d_in, const int* in_sizes, int n_in,
                              void* d_out, int out_size, void* d_ws, size_t ws_size,
                              hipStream_t stream) {
    const float* x    = (const float*)d_in[0];
    const float* ln1g = (const float*)d_in[1];
    const float* ln1b = (const float*)d_in[2];
    const float* Wk   = (const float*)d_in[3];
    const float* bk   = (const float*)d_in[4];
    const float* Wv   = (const float*)d_in[5];
    const float* bv   = (const float*)d_in[6];
    const float* Wq   = (const float*)d_in[7];
    const float* bq   = (const float*)d_in[8];
    const float* w    = (const float*)d_in[9];
    const float* Wo   = (const float*)d_in[10];
    const float* bo   = (const float*)d_in[11];
    const float* ln2g = (const float*)d_in[12];
    const float* ln2b = (const float*)d_in[13];
    const float* W1   = (const float*)d_in[14];
    const float* b1   = (const float*)d_in[15];
    const float* W2   = (const float*)d_in[16];
    const float* b2   = (const float*)d_in[17];
    float* out = (float*)d_out;

    const long S_BTD = (long)B_ * T_ * D_;      // 8,388,608
    const long S_TD  = (long)T_ * D_;           // 1,048,576
    const long S_TT  = (long)T_ * T_;           // 4,194,304
    const long S_B2D = (long)B_ * T_ * 2 * D_;  // 16,777,216
    const long S_DD  = (long)D_ * D_;           // 262,144

    // Workspace (bf16 elems unless noted) ~136 MB (mk slot retained but unused):
    bf16* h1     = (bf16*)d_ws;            // later h2 (both PACKED)
    bf16* outres = h1 + S_BTD;             // linear
    bf16* ew     = outres + S_BTD;         // PACKED
    bf16* KVQ    = ew + S_TT;              // K|V|Q planes (3*S_BTD), linear
    bf16* kv2t   = KVQ + 3 * S_BTD;        // S_B2D, PACKED+interleaved per batch
    bf16* mk     = kv2t + S_B2D;           // (unused slot, keeps offsets stable)
    bf16* WkT    = mk + 2 * S_TD;          // all weights PACKED
    bf16* WvT    = WkT + S_DD;
    bf16* WqT    = WvT + S_DD;
    bf16* WoT    = WqT + S_DD;
    bf16* W1T    = WoT + S_DD;             // [H,D]
    bf16* W2T    = W1T + (long)D_ * H_;    // [D,H]
    bf16* Kb  = KVQ;
    bf16* Vb  = KVQ + S_BTD;
    bf16* Qb  = KVQ + 2 * S_BTD;           // sigQ linear, then Yt in place (s7)
    bf16* hH  = KVQ;                       // PACKED; spans K|V planes (dead) + more
    bf16* h2  = h1;

    const int M = B_ * T_;  // 16384

    WT6 p;
    p.src[0] = Wk; p.src[1] = Wv; p.src[2] = Wq; p.src[3] = Wo; p.src[4] = W1; p.src[5] = W2;
    p.dst[0] = WkT; p.dst[1] = WvT; p.dst[2] = WqT; p.dst[3] = WoT; p.dst[4] = W1T; p.dst[5] = W2T;
    p.K[0] = p.K[1] = p.K[2] = p.K[3] = 512; p.K[4] = 512; p.K[5] = 2048;
    p.N[0] = p.N[1] = p.N[2] = p.N[3] = 512; p.N[4] = 2048; p.N[5] = 512;

    // 1. PREP: wtrans(6) + LN1 + expw in ONE launch
    prep_kernel<<<6144 + 16384 + 2048, 256, 0, stream>>>(p, x, ln1g, ln1b, h1, w, ew);
    // 2. K|V|sigQ GEMM: planes linear -> Kb,Vb,Qb (sigmoid on Q plane)
    mfma_gemm<128, 3><<<dim3(1536 / 128, M / 128, 1), 256, 0, stream>>>(
        h1, WkT, bk, bv, bq, Kb, nullptr, nullptr, nullptr, nullptr,
        M, 1536, D_, (1 << 4), 0, 0, S_BTD);
    // 3. MKV: fused max-over-batch + kv2t build (packed, 16-col num/den interleave)
    mkv_kernel<<<dim3(T_ / 64, D_ / 64), 256, 0, stream>>>(Kb, Vb, kv2t);
    // 4. FUSED s7: Yt = sigQ * (ew@expK*V)/(ew@expK), in place into Qb
    mfma_gemm<128, 3><<<dim3(1024 / 128, T_ / 128, B_), 256, 0, stream>>>(
        ew, kv2t, nullptr, nullptr, nullptr, nullptr, nullptr, nullptr, nullptr, Qb,
        T_, 1024, T_, 0, (long)1024 * T_, 0, 0);
    // 5. out = Yt@Wo + bo + x, C linear + f32 residual
    mfma_gemm<128, 2><<<dim3(D_ / 128, M / 128, 1), 256, 0, stream>>>(
        Qb, WoT, bo, nullptr, nullptr, outres, nullptr, nullptr, x, nullptr,
        M, D_, D_, 0, 0, 0, 0);
    // 6. h2 = LN2(out), packed
    ln_kernel<bf16, true><<<M, 256, 0, stream>>>(outres, ln2g, ln2b, h2);
    // 7. hH = gelu(h2@W1 + b1), C PACKED (= step-8 A)
    mfma_gemm<128, 7><<<dim3(H_ / 128, M / 128, 1), 256, 0, stream>>>(
        h2, W1T, b1, nullptr, nullptr, hH, nullptr, nullptr, nullptr, nullptr,
        M, H_, D_, 2, 0, 0, 0);
    // 8. y = gelu(hH@W2 + b2) + out -> f32 d_out
    mfma_gemm<128, 3><<<dim3(D_ / 128, M / 128, 1), 256, 0, stream>>>(
        hH, W2T, b2, nullptr, nullptr, nullptr, out, outres, nullptr, nullptr,
        M, D_, H_, 2, 0, 0, 0);
}

// Round 11
// 445.616 us; speedup vs baseline: 1.1722x; 1.1722x over previous
//
#include <hip/hip_runtime.h>
#include <hip/hip_bf16.h>
#include <math.h>

typedef __hip_bfloat16 bf16;
typedef __bf16 bf16x8 __attribute__((ext_vector_type(8)));
typedef float f32x4 __attribute__((ext_vector_type(4)));

#define B_ 8
#define T_ 2048
#define D_ 512
#define H_ 2048

__device__ __forceinline__ float b2f(unsigned short u) {
    return __uint_as_float((unsigned)u << 16);
}
__device__ __forceinline__ float ldf(const float* p, long i) { return p[i]; }
__device__ __forceinline__ float ldf(const bf16* p, long i) {
    return b2f(((const unsigned short*)p)[i]);
}
// tanh-form gelu: v*sigmoid(1.59577(v+0.044715 v^3)); |err| < 1e-3 abs
__device__ __forceinline__ float gelu_f(float v) {
    float a = 1.5957691216057308f * (v + 0.044715f * v * v * v);
    return v / (1.0f + __expf(-a));
}

// Packed (tile-major) layout for GEMM-staged operands:
// tile = 16 rows x 32 cols (1 KB bf16) = exactly one wave's global_load_lds
// payload in LDS dest order: within-tile offset = (row&15)*32 + (col&31).
//   off(row,col,K) = ((row>>4)*(K>>5) + (col>>5))*512 + (row&15)*32 + (col&31)
// => staging is fully-contiguous 1KB bursts (FETCH 138->25MB measured, R5).
__device__ __forceinline__ long poff(int row, int col, int K) {
    return ((long)(row >> 4) * (K >> 5) + (col >> 5)) * 512 + (row & 15) * 32 + (col & 31);
}

#define GLD16(g, l)                                                          \
    __builtin_amdgcn_global_load_lds(                                        \
        (const __attribute__((address_space(1))) void*)(g),                  \
        (__attribute__((address_space(3))) void*)(l), 16, 0, 0)

// ---------------- LayerNorm body over D=512, 256 threads, one row -----------------
template <typename Tin, bool PACKO>
__device__ __forceinline__ void ln_body(const Tin* __restrict__ x,
                                        const float* __restrict__ g,
                                        const float* __restrict__ bb,
                                        bf16* __restrict__ y, int row, int tid,
                                        float* red) {
    long base = (long)row * D_;
    float v0 = ldf(x, base + tid);
    float v1 = ldf(x, base + tid + 256);
    float s = v0 + v1;
#pragma unroll
    for (int off = 32; off > 0; off >>= 1) s += __shfl_down(s, off);
    int lane = tid & 63, wid = tid >> 6;
    if (lane == 0) red[wid] = s;
    __syncthreads();
    float mean = (red[0] + red[1] + red[2] + red[3]) * (1.0f / 512.0f);
    __syncthreads();
    float d0 = v0 - mean, d1 = v1 - mean;
    float vs = d0 * d0 + d1 * d1;
#pragma unroll
    for (int off = 32; off > 0; off >>= 1) vs += __shfl_down(vs, off);
    if (lane == 0) red[wid] = vs;
    __syncthreads();
    float var = (red[0] + red[1] + red[2] + red[3]) * (1.0f / 512.0f);
    float rstd = rsqrtf(var + 1e-5f);
    float o0 = d0 * rstd * g[tid] + bb[tid];
    float o1 = d1 * rstd * g[tid + 256] + bb[tid + 256];
    if (PACKO) {
        y[poff(row, tid, D_)]       = __float2bfloat16(o0);
        y[poff(row, tid + 256, D_)] = __float2bfloat16(o1);
    } else {
        y[base + tid]       = __float2bfloat16(o0);
        y[base + tid + 256] = __float2bfloat16(o1);
    }
}

// ---------------- standalone LN (step 6 only) ----------------
template <typename Tin, bool PACKO>
__global__ __launch_bounds__(256) void ln_kernel(const Tin* __restrict__ x,
                                                 const float* __restrict__ g,
                                                 const float* __restrict__ bb,
                                                 bf16* __restrict__ y) {
    __shared__ float red[4];
    ln_body<Tin, PACKO>(x, g, bb, y, blockIdx.x, threadIdx.x, red);
}

struct WT6 {
    const float* src[6];
    bf16* dst[6];
    int K[6], N[6];
};

// -------- PREP: one launch = wtrans(6144 blocks) + LN1(16384) + expw(2048) -------
// All three depend only on kernel inputs.
__global__ __launch_bounds__(256) void prep_kernel(WT6 p,
                                                   const float* __restrict__ x,
                                                   const float* __restrict__ ln1g,
                                                   const float* __restrict__ ln1b,
                                                   bf16* __restrict__ h1,
                                                   const float* __restrict__ w,
                                                   bf16* __restrict__ ew) {
    __shared__ float sbuf[64][65];
    int bid = blockIdx.x;
    int tid = threadIdx.x;
    if (bid < 6144) {
        // weight transpose + f32->bf16, PACKED: W[K,N] -> WT[N,K]
        int z = bid >> 10;
        int rem = bid & 1023;
        int n0 = (rem & 31) * 64, k0 = (rem >> 5) * 64;
        int K = p.K[z], N = p.N[z];
        if (n0 >= N || k0 >= K) return;
        const float* W = p.src[z];
        bf16* WT = p.dst[z];
        int tx = tid & 63, ty = tid >> 6;
#pragma unroll
        for (int r = 0; r < 16; ++r) {
            int kl = r * 4 + ty;
            sbuf[kl][tx] = W[(long)(k0 + kl) * N + n0 + tx];
        }
        __syncthreads();
#pragma unroll
        for (int r = 0; r < 16; ++r) {
            int nl = r * 4 + ty;
            WT[poff(n0 + nl, k0 + tx, K)] = __float2bfloat16(sbuf[tx][nl]);
        }
    } else if (bid < 6144 + 16384) {
        // LN1 (packed output)
        ln_body<float, true>(x, ln1g, ln1b, h1, bid - 6144, tid, &sbuf[0][0]);
    } else {
        // exp(w - rowmax(w)), packed output
        int row = bid - (6144 + 16384);
        long base = (long)row * T_;
        float v[8];
        float mx = -3.4e38f;
#pragma unroll
        for (int i = 0; i < 8; ++i) {
            v[i] = w[base + tid + i * 256];
            mx = fmaxf(mx, v[i]);
        }
#pragma unroll
        for (int off = 32; off > 0; off >>= 1) mx = fmaxf(mx, __shfl_down(mx, off));
        float* red = &sbuf[0][0];
        if ((tid & 63) == 0) red[tid >> 6] = mx;
        __syncthreads();
        float rmax = fmaxf(fmaxf(red[0], red[1]), fmaxf(red[2], red[3]));
#pragma unroll
        for (int i = 0; i < 8; ++i)
            ew[poff(row, tid + i * 256, T_)] = __float2bfloat16(expf(v[i] - rmax));
    }
}

// ---- max over batch dim of K [B,T,D] -> mk [T*D] (bf16: max of bf16 is exact) ----
// (R10 lesson: fusing this into kv2t shrank the grid to 256 blocks = 1/CU and
//  cost ~+35us of lost HBM BW — keep the two wide launches. Guideline 11.)
__global__ __launch_bounds__(256) void maxk_kernel(const bf16* __restrict__ K,
                                                   bf16* __restrict__ mk) {
    long i = (long)blockIdx.x * 256 + threadIdx.x;
    float m = ldf(K, i);
#pragma unroll
    for (int b = 1; b < B_; ++b) m = fmaxf(m, ldf(K, (long)b * (T_ * D_) + i));
    mk[i] = __float2bfloat16(m);
}

// ------- build kv2T[b][n][t] PACKED with 16-col-group num/den interleave:
//   d -> num_row = (d>>4)*32 + (d&15), den_row = num_row + 16
// so in s7 a wave's ni-even fragment is num and ni-odd the SAME d's den (same
// lane) -> divergence-free fused-Yt epilogue.
__global__ __launch_bounds__(256) void kv2t_kernel(const bf16* __restrict__ K_,
                                                   const bf16* __restrict__ V_,
                                                   const bf16* __restrict__ mk,
                                                   bf16* __restrict__ kv2t) {
    __shared__ float sev[64][65];
    __shared__ float se[64][65];
    int tx = threadIdx.x & 63, ty = threadIdx.x >> 6;
    int t0 = blockIdx.x * 64, d0 = blockIdx.y * 64, b = blockIdx.z;
    long ibase = (long)b << 20;
#pragma unroll
    for (int r = 0; r < 16; ++r) {
        int tl = r * 4 + ty;
        long mi = (long)(t0 + tl) * D_ + d0 + tx;
        float e = expf(ldf(K_, ibase + mi) - ldf(mk, mi));
        sev[tl][tx] = e * ldf(V_, ibase + mi);
        se[tl][tx] = e;
    }
    __syncthreads();
    long obase = (long)b << 21;
#pragma unroll
    for (int r = 0; r < 16; ++r) {
        int d = d0 + r * 4 + ty;
        int nrow = ((d >> 4) << 5) + (d & 15);
        kv2t[obase + poff(nrow,      t0 + tx, T_)] = __float2bfloat16(sev[tx][r * 4 + ty]);
        kv2t[obase + poff(nrow + 16, t0 + tx, T_)] = __float2bfloat16(se[tx][r * 4 + ty]);
    }
}

// ---------------- MFMA GEMM: C = epi(A@Bt^T + bias) [+res] ------------------------
// R6-proven body: 128x128 macro-tile, 4 waves, 2-buffer LDS, plain C++ LDS reads,
// __syncthreads per K-step, packed 1KB-burst staging, 3D chunked XCD swizzle.
// yq != null (s4 only): FUSED-Yt epilogue, divergence-free. B rows carry
// 16-col-group interleaved num/den (see kv2t): acc[mi][2p]=num, acc[mi][2p+1]=den
// for d = (n0+wn*64)/2 + p*16 + cc. Writes Yt = sigQ*num/den in place into yq.
// PK bit0: A packed; bit1: B packed; bit2: C written packed (non-plane path).
// planeStride!=0: N split into 512-col planes; per-plane bias b0/b1/b2 and
// mode=(modes>>(2*plane))&3. mode 0=none 1=sigmoid 2=gelu.
template <int BM, int PK>
__global__ __launch_bounds__(256, 4) void mfma_gemm(
    const bf16* __restrict__ A, const bf16* __restrict__ Bt,
    const float* __restrict__ b0, const float* __restrict__ b1,
    const float* __restrict__ b2,
    bf16* __restrict__ Cb, float* __restrict__ Cf,
    const bf16* __restrict__ resb, const float* __restrict__ resf,
    bf16* __restrict__ yq,
    int M, int N, int K, int modes, long bsB, long bsC, long planeStride) {
    constexpr int MI = BM / 32;
    constexpr int NA = BM / 64;
    constexpr int PL = (BM + 128) * 32;  // shorts per LDS buffer plane
    constexpr bool PA = PK & 1, PB = PK & 2, PCK = PK & 4;
    constexpr long astep = PA ? 512 : 32;
    constexpr long bstep = PB ? 512 : 32;
    __shared__ short Sh[2 * PL];         // 2 bufs: 32KB @BM=128
    int tid = threadIdx.x;
    int lane = tid & 63, wave = tid >> 6;
    int wm = wave & 1, wn = wave >> 1;

    // 3D chunked XCD swizzle (nwg % 8 == 0 for every launch here)
    int gx = gridDim.x, gy = gridDim.y;
    long nwg = (long)gx * gy * gridDim.z;
    long o = blockIdx.x + (long)gx * (blockIdx.y + (long)gy * blockIdx.z);
    long wk = (o & 7) * (nwg >> 3) + (o >> 3);
    int bx = (int)(wk % gx);
    long rq = wk / gx;
    int by = (int)(rq % gy);
    int bz = (int)(rq / gy);
    int m0 = by * BM, n0 = bx * 128;

    const short* Ag = (const short*)A;
    const short* Bg = (const short*)Bt + (long)bz * bsB;

    int lr = lane >> 2;
    int le = (lane & 3) * 8;
    const short* ga[NA];
    short* la[NA];
#pragma unroll
    for (int i = 0; i < NA; ++i) {
        int arow = m0 + wave * (BM / 4) + i * 16;
        ga[i] = PA ? Ag + (long)(arow >> 4) * ((long)K << 4) + lane * 8
                   : Ag + (long)(arow + lr) * K + le;
        la[i] = Sh + (wave * (BM / 4) + i * 16) * 32;
    }
    int brow = n0 + wave * 32;
    const short* gb0 = PB ? Bg + (long)(brow >> 4) * ((long)K << 4) + lane * 8
                          : Bg + (long)(brow + lr) * K + le;
    const short* gb1 = PB ? gb0 + ((long)K << 4) : gb0 + 16L * K;
    short* lb0 = Sh + BM * 32 + (wave * 32) * 32;
    short* lb1 = lb0 + 16 * 32;

    f32x4 acc[MI][4];
    f32x4 zz = {0.f, 0.f, 0.f, 0.f};
#pragma unroll
    for (int i = 0; i < MI; ++i)
#pragma unroll
        for (int j = 0; j < 4; ++j) acc[i][j] = zz;

    int fr = lane & 15;
    int fk = (lane >> 4) * 8;
    int rm = wm * (BM / 2);

    auto stage = [&](int kt, int ofs) {
#pragma unroll
        for (int i = 0; i < NA; ++i) GLD16(ga[i] + kt * astep, la[i] + ofs);
        GLD16(gb0 + kt * bstep, lb0 + ofs);
        GLD16(gb1 + kt * bstep, lb1 + ofs);
    };
    auto compute = [&](int ofs) {
        const short* Asb = Sh + ofs;
        const short* Bsb = Sh + ofs + BM * 32;
        bf16x8 af[MI], bv[4];
#pragma unroll
        for (int mi = 0; mi < MI; ++mi)
            af[mi] = *(const bf16x8*)(Asb + (rm + mi * 16 + fr) * 32 + fk);
#pragma unroll
        for (int ni = 0; ni < 4; ++ni)
            bv[ni] = *(const bf16x8*)(Bsb + (wn * 64 + ni * 16 + fr) * 32 + fk);
#pragma unroll
        for (int mi = 0; mi < MI; ++mi)
#pragma unroll
            for (int ni = 0; ni < 4; ++ni)
                acc[mi][ni] = __builtin_amdgcn_mfma_f32_16x16x32_bf16(
                    af[mi], bv[ni], acc[mi][ni], 0, 0, 0);
    };

    // ---- 2-buffer pipelined K loop (nk even for all shapes used: K=512/2048) ----
    int nk = K >> 5;
    stage(0, 0);
    __syncthreads();
    for (int kt = 0; kt < nk; kt += 2) {
        if (kt + 1 < nk) stage(kt + 1, PL);
        compute(0);
        __syncthreads();
        if (kt + 2 < nk) stage(kt + 2, 0);
        compute(PL);
        __syncthreads();
    }

    int cc = lane & 15, cr = (lane >> 4) * 4;
    if (yq) {
        // ---- fused-Yt epilogue (s4): all lanes active, no shfl ----
        long qb = (long)bz * (long)(T_ * D_);
        int dbase = (n0 + wn * 64) >> 1;
#pragma unroll
        for (int mi = 0; mi < MI; ++mi) {
            int row0 = m0 + rm + mi * 16 + cr;
#pragma unroll
            for (int pp = 0; pp < 2; ++pp) {
                int d = dbase + pp * 16 + cc;
#pragma unroll
                for (int r = 0; r < 4; ++r) {
                    long qi = qb + (long)(row0 + r) * D_ + d;
                    float sq = ldf((const bf16*)yq, qi);
                    yq[qi] = __float2bfloat16(sq * acc[mi][2 * pp][r] /
                                              acc[mi][2 * pp + 1][r]);
                }
            }
        }
        return;
    }
    long cbase = (long)bz * bsC;
#pragma unroll
    for (int mi = 0; mi < MI; ++mi) {
#pragma unroll
        for (int ni = 0; ni < 4; ++ni) {
            int row0 = m0 + rm + mi * 16 + cr;
            int col = n0 + wn * 64 + ni * 16 + cc;
            float bvl;
            long colterm;
            int md, rowstride;
            if (planeStride) {
                int plane = col >> 9;
                int c2 = col & 511;
                const float* bp = (plane == 0) ? b0 : ((plane == 1) ? b1 : b2);
                bvl = bp[c2];
                md = (modes >> (2 * plane)) & 3;
                colterm = (long)plane * planeStride + c2;
                rowstride = 512;
            } else {
                bvl = b0 ? b0[col] : 0.0f;
                md = modes & 3;
                colterm = col;
                rowstride = N;
            }
#pragma unroll
            for (int r = 0; r < 4; ++r) {
                float v = acc[mi][ni][r] + bvl;
                if (md == 1) v = 1.0f / (1.0f + __expf(-v));
                else if (md == 2) v = gelu_f(v);
                long idx;
                if (PCK) idx = cbase + poff(row0 + r, col, N);
                else     idx = cbase + (long)(row0 + r) * rowstride + colterm;
                if (resf) v += resf[idx];
                if (resb) v += ldf(resb, idx);
                if (Cf) Cf[idx] = v;
                else Cb[idx] = __float2bfloat16(v);
            }
        }
    }
}

extern "C" void kernel_launch(void* const* d_in, const int* in_sizes, int n_in,
                              void* d_out, int out_size, void* d_ws, size_t ws_size,
                              hipStream_t stream) {
    const float* x    = (const float*)d_in[0];
    const float* ln1g = (const float*)d_in[1];
    const float* ln1b = (const float*)d_in[2];
    const float* Wk   = (const float*)d_in[3];
    const float* bk   = (const float*)d_in[4];
    const float* Wv   = (const float*)d_in[5];
    const float* bv   = (const float*)d_in[6];
    const float* Wq   = (const float*)d_in[7];
    const float* bq   = (const float*)d_in[8];
    const float* w    = (const float*)d_in[9];
    const float* Wo   = (const float*)d_in[10];
    const float* bo   = (const float*)d_in[11];
    const float* ln2g = (const float*)d_in[12];
    const float* ln2b = (const float*)d_in[13];
    const float* W1   = (const float*)d_in[14];
    const float* b1   = (const float*)d_in[15];
    const float* W2   = (const float*)d_in[16];
    const float* b2   = (const float*)d_in[17];
    float* out = (float*)d_out;

    const long S_BTD = (long)B_ * T_ * D_;      // 8,388,608
    const long S_TD  = (long)T_ * D_;           // 1,048,576
    const long S_TT  = (long)T_ * T_;           // 4,194,304
    const long S_B2D = (long)B_ * T_ * 2 * D_;  // 16,777,216
    const long S_DD  = (long)D_ * D_;           // 262,144

    // Workspace (bf16 elems unless noted) ~136 MB:
    bf16* h1     = (bf16*)d_ws;            // later h2 (both PACKED)
    bf16* outres = h1 + S_BTD;             // linear
    bf16* ew     = outres + S_BTD;         // PACKED
    bf16* KVQ    = ew + S_TT;              // K|V|Q planes (3*S_BTD), linear
    bf16* kv2t   = KVQ + 3 * S_BTD;        // S_B2D, PACKED+interleaved per batch
    bf16* mk     = kv2t + S_B2D;           // S_TD bf16
    bf16* WkT    = mk + 2 * S_TD;          // all weights PACKED
    bf16* WvT    = WkT + S_DD;
    bf16* WqT    = WvT + S_DD;
    bf16* WoT    = WqT + S_DD;
    bf16* W1T    = WoT + S_DD;             // [H,D]
    bf16* W2T    = W1T + (long)D_ * H_;    // [D,H]
    bf16* Kb  = KVQ;
    bf16* Vb  = KVQ + S_BTD;
    bf16* Qb  = KVQ + 2 * S_BTD;           // sigQ linear, then Yt in place (s4)
    bf16* hH  = KVQ;                       // PACKED; spans K|V planes (dead) + more
    bf16* h2  = h1;

    const int M = B_ * T_;  // 16384

    WT6 p;
    p.src[0] = Wk; p.src[1] = Wv; p.src[2] = Wq; p.src[3] = Wo; p.src[4] = W1; p.src[5] = W2;
    p.dst[0] = WkT; p.dst[1] = WvT; p.dst[2] = WqT; p.dst[3] = WoT; p.dst[4] = W1T; p.dst[5] = W2T;
    p.K[0] = p.K[1] = p.K[2] = p.K[3] = 512; p.K[4] = 512; p.K[5] = 2048;
    p.N[0] = p.N[1] = p.N[2] = p.N[3] = 512; p.N[4] = 2048; p.N[5] = 512;

    // 1. PREP: wtrans(6) + LN1 + expw in ONE launch
    prep_kernel<<<6144 + 16384 + 2048, 256, 0, stream>>>(p, x, ln1g, ln1b, h1, w, ew);
    // 2. K|V|sigQ GEMM: planes linear -> Kb,Vb,Qb (sigmoid on Q plane)
    mfma_gemm<128, 3><<<dim3(1536 / 128, M / 128, 1), 256, 0, stream>>>(
        h1, WkT, bk, bv, bq, Kb, nullptr, nullptr, nullptr, nullptr,
        M, 1536, D_, (1 << 4), 0, 0, S_BTD);
    // 3a. mk = max_b K (wide grid, bf16); 3b. kv2t packed + 16-col interleave
    maxk_kernel<<<S_TD / 256, 256, 0, stream>>>(Kb, mk);
    kv2t_kernel<<<dim3(T_ / 64, D_ / 64, B_), 256, 0, stream>>>(Kb, Vb, mk, kv2t);
    // 4. FUSED s7: Yt = sigQ * (ew@expK*V)/(ew@expK), in place into Qb
    mfma_gemm<128, 3><<<dim3(1024 / 128, T_ / 128, B_), 256, 0, stream>>>(
        ew, kv2t, nullptr, nullptr, nullptr, nullptr, nullptr, nullptr, nullptr, Qb,
        T_, 1024, T_, 0, (long)1024 * T_, 0, 0);
    // 5. out = Yt@Wo + bo + x, C linear + f32 residual
    mfma_gemm<128, 2><<<dim3(D_ / 128, M / 128, 1), 256, 0, stream>>>(
        Qb, WoT, bo, nullptr, nullptr, outres, nullptr, nullptr, x, nullptr,
        M, D_, D_, 0, 0, 0, 0);
    // 6. h2 = LN2(out), packed
    ln_kernel<bf16, true><<<M, 256, 0, stream>>>(outres, ln2g, ln2b, h2);
    // 7. hH = gelu(h2@W1 + b1), C PACKED (= step-8 A)
    mfma_gemm<128, 7><<<dim3(H_ / 128, M / 128, 1), 256, 0, stream>>>(
        h2, W1T, b1, nullptr, nullptr, hH, nullptr, nullptr, nullptr, nullptr,
        M, H_, D_, 2, 0, 0, 0);
    // 8. y = gelu(hH@W2 + b2) + out -> f32 d_out
    mfma_gemm<128, 3><<<dim3(D_ / 128, M / 128, 1), 256, 0, stream>>>(
        hH, W2T, b2, nullptr, nullptr, nullptr, out, outres, nullptr, nullptr,
        M, D_, H_, 2, 0, 0, 0);
}